// Round 1
// baseline (181.130 us; speedup 1.0000x reference)
//
#include <hip/hip_runtime.h>

#define BDIM 256

constexpr int Vv = 3, Cc = 64, Hh = 96, Ww = 96, Dd = 48;
constexpr int HW = Hh * Ww;          // 9216
constexpr int NPIX = Dd * HW;        // 442368
constexpr int DHW = Dd * HW;         // output channel stride

// ---------------------------------------------------------------------------
// Shared coordinate/weight computation (identical numerics to verified pass).
// ---------------------------------------------------------------------------
__device__ __forceinline__ void compute_warp(const float* __restrict__ proj, float depth,
                                             float xf, float yf,
                                             int offs[2][4], float wts[2][4], float& msum)
{
    msum = 1.0f;
#pragma unroll
    for (int v = 0; v < 2; ++v) {
#pragma clang fp contract(off)
        const float* P = proj + (v + 1) * 12;
        const float r00 = P[0], r01 = P[1], r02 = P[2],  t0 = P[3];
        const float r10 = P[4], r11 = P[5], r12 = P[6],  t1 = P[7];
        const float r20 = P[8], r21 = P[9], r22 = P[10], t2 = P[11];

        const float px = ((r00 * xf + r01 * yf) + r02) + t0 / depth;
        const float py = ((r10 * xf + r11 * yf) + r12) + t1 / depth;
        const float pz = ((r20 * xf + r21 * yf) + r22) + t2 / depth;

        const float xy0 = px / pz;
        const float xy1 = py / pz;
        const float gx = xy0 / ((float)(Ww - 1) * 0.5f) - 1.0f;
        const float gy = xy1 / ((float)(Hh - 1) * 0.5f) - 1.0f;

        const bool inb = (gx > -1.0f) && (gx < 1.0f) && (gy > -1.0f) && (gy < 1.0f);
        msum += inb ? 1.0f : 0.0f;

        const float sx = (gx + 1.0f) * 0.5f * (float)(Ww - 1);
        const float sy = (gy + 1.0f) * 0.5f * (float)(Hh - 1);
        const float x0 = floorf(sx), y0 = floorf(sy);
        const float wx1 = sx - x0, wy1 = sy - y0;
        const float wx0 = 1.0f - wx1, wy0 = 1.0f - wy1;

#pragma unroll
        for (int k = 0; k < 4; ++k) {
            const float xi = (k & 1) ? (x0 + 1.0f) : x0;
            const float yi = (k & 2) ? (y0 + 1.0f) : y0;
            const float wk = ((k & 1) ? wx1 : wx0) * ((k & 2) ? wy1 : wy0);
            const bool valid = (xi >= 0.0f) && (xi <= (float)(Ww - 1)) &&
                               (yi >= 0.0f) && (yi <= (float)(Hh - 1));
            const float xc = fminf(fmaxf(xi, 0.0f), (float)(Ww - 1));
            const float yc = fminf(fmaxf(yi, 0.0f), (float)(Hh - 1));
            offs[v][k] = (int)yc * Ww + (int)xc;
            wts[v][k] = valid ? wk : 0.0f;
        }
    }
}

__device__ __forceinline__ float var_one(float fr, float a1, float a2, float cnt)
{
    const float s  = fr + a1 + a2;
    const float q  = fr * fr + a1 * a1 + a2 * a2;
    const float sc = s * cnt;
    return q * cnt - sc * sc;
}

// ---------------------------------------------------------------------------
// feats (V, C, HW) -> ftr (V, HW, C)   (channel-minor for coalesced reads)
// ---------------------------------------------------------------------------
__global__ void __launch_bounds__(BDIM) transpose_feats_kernel(const float* __restrict__ feats,
                                                               float* __restrict__ ft)
{
    __shared__ float tile[64][65];
    const int v  = blockIdx.y;
    const int p0 = blockIdx.x * 64;
    const float* src = feats + (size_t)v * Cc * HW;

    const int px = threadIdx.x & 63;
    const int c0 = threadIdx.x >> 6;
#pragma unroll
    for (int c = c0; c < Cc; c += 4)
        tile[c][px] = src[(size_t)c * HW + p0 + px];
    __syncthreads();

    const int cc  = threadIdx.x & 63;
    const int pr0 = threadIdx.x >> 6;
    float* dst = ft + ((size_t)v * HW + p0) * Cc;
#pragma unroll
    for (int p = pr0; p < 64; p += 4)
        dst[p * Cc + cc] = tile[cc][p];
}

// ---------------------------------------------------------------------------
// main kernel: one block per (d, h) row of 96 pixels.
// Phase 1: per-pixel warp coords -> LDS; ref-img copy + warped-img channels.
// Phase 2: wave handles 4 pixels/iter, lane = (pixel-sub, channel-quad);
//          every gather is a float4 (global_load_dwordx4, 1 KB/wave-instr).
// Phase 3: coalesced store of the 64x96 variance tile.
// ---------------------------------------------------------------------------
__global__ void __launch_bounds__(BDIM) ge_row_kernel(
    const float* __restrict__ imgs, const float* __restrict__ ftr,
    const float* __restrict__ proj, const float* __restrict__ depthv,
    float* __restrict__ out)
{
    __shared__ float s_tile[Cc][Ww + 1];                // 64 x 97 floats, bank-safe
    __shared__ alignas(16) int   s_base[2][Ww][4];      // int4 per (view,pixel)
    __shared__ alignas(16) float s_wt[2][Ww][4];        // float4 per (view,pixel)
    __shared__ float s_cnt[Ww];

    const int blk = blockIdx.x;              // d*Hh + h
    const int d   = blk / Hh;
    const int h   = blk % Hh;
    const int tid = threadIdx.x;
    const int rowbase = d * HW + h * Ww;     // output offset of (d,h,0)

    // ---- Phase 1 ----
    if (tid < Ww) {
        const int w = tid;
        int offs[2][4];
        float wts[2][4];
        float msum;
        compute_warp(proj, depthv[d], (float)w, (float)h, offs, wts, msum);
        s_cnt[w] = 1.0f / msum;
#pragma unroll
        for (int v = 0; v < 2; ++v)
#pragma unroll
            for (int k = 0; k < 4; ++k) {
                s_base[v][w][k] = ((v + 1) * HW + offs[v][k]) * Cc;
                s_wt[v][w][k]   = wts[v][k];
            }

        const int hw = h * Ww + w;
        // channels 0..2: ref image broadcast over depth
#pragma unroll
        for (int c = 0; c < 3; ++c)
            out[c * DHW + rowbase + w] = imgs[c * HW + hw];

        // channels 3..8: warped images
#pragma unroll
        for (int v = 0; v < 2; ++v) {
            const float* ib = imgs + (size_t)(v + 1) * 3 * HW;
#pragma unroll
            for (int c = 0; c < 3; ++c) {
                const float* p = ib + (size_t)c * HW;
                const float acc = wts[v][0] * p[offs[v][0]] + wts[v][1] * p[offs[v][1]] +
                                  wts[v][2] * p[offs[v][2]] + wts[v][3] * p[offs[v][3]];
                out[(3 * (v + 1) + c) * DHW + rowbase + w] = acc;
            }
        }
    }
    __syncthreads();

    // ---- Phase 2 ----
    {
        const int wave = tid >> 6;
        const int lane = tid & 63;
        const int sub  = lane >> 4;          // pixel-within-quad 0..3
        const int c4   = (lane & 15) << 2;   // channel quad 0,4,...,60
        const int p0   = wave * (Ww / 4);    // 24 pixels per wave
#pragma unroll 2
        for (int i = 0; i < Ww / 16; ++i) {  // 6 iterations, 4 pixels each
            const int p = p0 + i * 4 + sub;
            const float cnt = s_cnt[p];
            const int4   b0 = *reinterpret_cast<const int4*>(&s_base[0][p][0]);
            const int4   b1 = *reinterpret_cast<const int4*>(&s_base[1][p][0]);
            const float4 w0 = *reinterpret_cast<const float4*>(&s_wt[0][p][0]);
            const float4 w1 = *reinterpret_cast<const float4*>(&s_wt[1][p][0]);

            const float4 fr  = *reinterpret_cast<const float4*>(ftr + (size_t)(h * Ww + p) * Cc + c4);
            const float4 v00 = *reinterpret_cast<const float4*>(ftr + b0.x + c4);
            const float4 v01 = *reinterpret_cast<const float4*>(ftr + b0.y + c4);
            const float4 v02 = *reinterpret_cast<const float4*>(ftr + b0.z + c4);
            const float4 v03 = *reinterpret_cast<const float4*>(ftr + b0.w + c4);
            const float4 v10 = *reinterpret_cast<const float4*>(ftr + b1.x + c4);
            const float4 v11 = *reinterpret_cast<const float4*>(ftr + b1.y + c4);
            const float4 v12 = *reinterpret_cast<const float4*>(ftr + b1.z + c4);
            const float4 v13 = *reinterpret_cast<const float4*>(ftr + b1.w + c4);

            {
                const float a1 = w0.x * v00.x + w0.y * v01.x + w0.z * v02.x + w0.w * v03.x;
                const float a2 = w1.x * v10.x + w1.y * v11.x + w1.z * v12.x + w1.w * v13.x;
                s_tile[c4 + 0][p] = var_one(fr.x, a1, a2, cnt);
            }
            {
                const float a1 = w0.x * v00.y + w0.y * v01.y + w0.z * v02.y + w0.w * v03.y;
                const float a2 = w1.x * v10.y + w1.y * v11.y + w1.z * v12.y + w1.w * v13.y;
                s_tile[c4 + 1][p] = var_one(fr.y, a1, a2, cnt);
            }
            {
                const float a1 = w0.x * v00.z + w0.y * v01.z + w0.z * v02.z + w0.w * v03.z;
                const float a2 = w1.x * v10.z + w1.y * v11.z + w1.z * v12.z + w1.w * v13.z;
                s_tile[c4 + 2][p] = var_one(fr.z, a1, a2, cnt);
            }
            {
                const float a1 = w0.x * v00.w + w0.y * v01.w + w0.z * v02.w + w0.w * v03.w;
                const float a2 = w1.x * v10.w + w1.y * v11.w + w1.z * v12.w + w1.w * v13.w;
                s_tile[c4 + 3][p] = var_one(fr.w, a1, a2, cnt);
            }
        }
    }
    __syncthreads();

    // ---- Phase 3 ----
#pragma unroll
    for (int idx = tid; idx < Cc * Ww; idx += BDIM) {
        const int cc = idx / Ww;
        const int p  = idx - cc * Ww;
        out[(9 + cc) * DHW + rowbase + p] = s_tile[cc][p];
    }
}

// ---------------------------------------------------------------------------
// fallback (no workspace needed) — only used if ws_size is too small
// ---------------------------------------------------------------------------
__global__ void __launch_bounds__(BDIM) ge_direct_kernel(
    const float* __restrict__ imgs, const float* __restrict__ feats,
    const float* __restrict__ proj, const float* __restrict__ depthv,
    float* __restrict__ out)
{
    const int idx = blockIdx.x * BDIM + threadIdx.x;
    if (idx >= NPIX) return;
    const int w = idx % Ww;
    const int t = idx / Ww;
    const int h = t % Hh;
    const int d = t / Hh;
    const int ohw = h * Ww + w;

    int offs[2][4];
    float wts[2][4];
    float msum;
    compute_warp(proj, depthv[d], (float)w, (float)h, offs, wts, msum);

    const int obase = d * HW + ohw;
#pragma unroll
    for (int c = 0; c < 3; ++c)
        out[c * DHW + obase] = imgs[c * HW + ohw];

#pragma unroll
    for (int v = 0; v < 2; ++v) {
        const float* ib = imgs + (size_t)(v + 1) * 3 * HW;
#pragma unroll
        for (int c = 0; c < 3; ++c) {
            const float* p = ib + (size_t)c * HW;
            const float acc = wts[v][0] * p[offs[v][0]] + wts[v][1] * p[offs[v][1]] +
                              wts[v][2] * p[offs[v][2]] + wts[v][3] * p[offs[v][3]];
            out[(3 * (v + 1) + c) * DHW + obase] = acc;
        }
    }

    const float count = 1.0f / msum;
    const float* f0 = feats;
    const float* f1 = feats + (size_t)Cc * HW;
    const float* f2 = feats + (size_t)2 * Cc * HW;
#pragma unroll 8
    for (int c = 0; c < Cc; ++c) {
        const float fr = f0[(size_t)c * HW + ohw];
        const float* p1 = f1 + (size_t)c * HW;
        const float* p2 = f2 + (size_t)c * HW;
        const float a1 = wts[0][0] * p1[offs[0][0]] + wts[0][1] * p1[offs[0][1]] +
                         wts[0][2] * p1[offs[0][2]] + wts[0][3] * p1[offs[0][3]];
        const float a2 = wts[1][0] * p2[offs[1][0]] + wts[1][1] * p2[offs[1][1]] +
                         wts[1][2] * p2[offs[1][2]] + wts[1][3] * p2[offs[1][3]];
        const float s = fr + a1 + a2;
        const float sq = fr * fr + a1 * a1 + a2 * a2;
        const float sc = s * count;
        out[(3 * Vv + c) * DHW + obase] = sq * count - sc * sc;
    }
}

extern "C" void kernel_launch(void* const* d_in, const int* in_sizes, int n_in,
                              void* d_out, int out_size, void* d_ws, size_t ws_size,
                              hipStream_t stream)
{
    const float* imgs   = (const float*)d_in[0];
    const float* feats  = (const float*)d_in[1];
    const float* proj   = (const float*)d_in[2];
    const float* depthv = (const float*)d_in[3];
    float* out = (float*)d_out;

    const size_t need = (size_t)Vv * HW * Cc * sizeof(float);   // 7.08 MB

    if (ws_size >= need) {
        float* ftr = (float*)d_ws;
        dim3 g1(HW / 64, Vv);
        transpose_feats_kernel<<<g1, BDIM, 0, stream>>>(feats, ftr);
        ge_row_kernel<<<Dd * Hh, BDIM, 0, stream>>>(imgs, ftr, proj, depthv, out);
    } else {
        const int blocks = (NPIX + BDIM - 1) / BDIM;
        ge_direct_kernel<<<blocks, BDIM, 0, stream>>>(imgs, feats, proj, depthv, out);
    }
}